// Round 8
// baseline (133.125 us; speedup 1.0000x reference)
//
#include <hip/hip_runtime.h>
#include <hip/hip_bf16.h>
#include <stdint.h>

#define NROWS 8192
#define NDIM  512
#define MARGIN 0.3f
#define NT    2080     // 64*65/2 upper-triangular 128x128 blocks

typedef __attribute__((ext_vector_type(16))) float floatx16;
typedef __attribute__((ext_vector_type(8)))  int   intx8;

// pack 4 floats -> 4 OCP e4m3 bytes (HW cvt, RNE, saturating)
__device__ inline unsigned cvt4_fp8(float4 f) {
  int v = 0;
  v = __builtin_amdgcn_cvt_pk_fp8_f32(f.x, f.y, v, false);
  v = __builtin_amdgcn_cvt_pk_fp8_f32(f.z, f.w, v, true);
  return (unsigned)v;
}

// fp32 -> fp8 e4m3, fully coalesced: lane i reads float4 i, writes u32 i.
// Block 0 thread 0 also zero-inits the fused-reduce accumulator+counter
// (stream-ordered before loss_kernel).
__global__ void convert_kernel(const float4* __restrict__ in, unsigned* __restrict__ out,
                               float* __restrict__ gacc, unsigned* __restrict__ gcnt) {
  int i = blockIdx.x * blockDim.x + threadIdx.x;
  if (i == 0) { *gacc = 0.f; *gcnt = 0u; }
  out[i] = cvt4_fp8(in[i]);
}

__device__ inline void gload_lds16(const void* g, void* l) {
  __builtin_amdgcn_global_load_lds(
      (const __attribute__((address_space(1))) unsigned int*)g,
      (__attribute__((address_space(3))) unsigned int*)l, 16, 0, 0);
}

// R23: FULL-OCCUPANCY variant. Occupancy ladder measured across R0-R7:
// 8 waves/CU = 48-53us, 12 = 42-44us, 16 = ~38us — latency-bound, scaling
// with resident waves. Per m69 occupancy steps at VGPR=64/128/256, so the
// only step past 16 waves/CU is <=64 regs/wave: ONE 32x32 MFMA tile per
// wave (acc = 16 AGPR, frags 16, 1 staging addr, ~10 misc ~= 55 live).
// 128x128 tile = 16 waves (1024 thr), __launch_bounds__(1024,8) pins 64
// regs -> 8 waves/SIMD; LDS 3-stage x 16 KB = 48 KB -> 2 blocks/CU ->
// 32 waves/CU (hardware max). Pipeline skeleton unchanged (R15-proven):
// distance-2 prefetch, per-wave counted vmcnt (1 DMA load/wave/stage ->
// steady vmcnt(1), never 0 until last), raw s_barrier (no lgkm drain),
// stage-after-barrier (WAR on 3rd buffer barrier-ordered), R14 swizzle.
// Final reduce fused: per-block atomicAdd + completion counter (m20:
// global atomics are device-scope), last block writes out.
__launch_bounds__(1024, 8)
__global__ void loss_kernel(const unsigned char* __restrict__ Xb, const int* __restrict__ tg,
                            float* __restrict__ gacc, unsigned* __restrict__ gcnt,
                            float* __restrict__ out) {
  __shared__ __align__(16) unsigned char As[3][8192];   // 128 rows x 64 B
  __shared__ __align__(16) unsigned char Bs[3][8192];
  __shared__ float red[16];

  // super-tile decode (8 diagonal supers of 36, then 28 off-diag of 64) —
  // exact R0 decode.
  int t = blockIdx.x;
  int bi, bj;
  if (t < 288) {
    int si = t / 36;
    int q  = t - si * 36;
    int ii = 0;
    while (q >= 8 - ii) { q -= 8 - ii; ii++; }
    bi = si * 8 + ii;
    bj = si * 8 + ii + q;
  } else {
    int q = t - 288;
    int s = q >> 6, r = q & 63;
    int si = 0;
    while (s >= 7 - si) { s -= 7 - si; si++; }
    int sj = si + 1 + s;
    bi = si * 8 + (r >> 3);
    bj = sj * 8 + (r & 7);
  }

  const int tid  = threadIdx.x;
  const int lane = tid & 63;
  const int w    = tid >> 6;             // 0..15
  const int wm   = w >> 2, wn = w & 3;   // 4x4 waves, 32x32 each
  const int g    = lane >> 5;            // MFMA k-group (0/1)
  const int m32  = lane & 31;            // MFMA row/col within 32

  const int rowBase = bi * 128;
  const int colBase = bj * 128;

  // staging: each tile = 128 rows x 64 B = 8 chunks of 1 KB (16 rows).
  // Wave w<8 stages A chunk w; wave w>=8 stages B chunk w-8 (ONE DMA
  // load/wave/stage). Chunk lane d: row = ch*16 + (d>>2), u_phys = d&3;
  // fetches global k-unit u_log = u_phys ^ ((srow>>2)&3) (conflict-free
  // b128 reads, R14-verified; ch*16 contributes 0 mod 4 to row>>2).
  const int srow = lane >> 2;
  const int sup  = lane & 3;
  const int ul   = sup ^ ((srow >> 2) & 3);
  const int ch   = w & 7;
  const int rloc = ch * 16 + srow;
  const unsigned gS = (unsigned)((((w < 8) ? rowBase : colBase) + rloc) * NDIM + ul * 16);
  unsigned char* ldsB = ((w < 8) ? &As[0][0] : &Bs[0][0]) + ch * 1024;

#define STAGE(KT, BUF) gload_lds16(Xb + gS + (KT) * 64, ldsB + (BUF) * 8192)

  floatx16 acc = (floatx16)(0.f);

  STAGE(0, 0);
  STAGE(1, 1);

#pragma unroll
  for (int kt = 0; kt < 8; kt++) {
    const int buf = kt % 3;
    // own stage kt landed (oldest load retired); kt+1's load stays in flight.
    if (kt < 7) asm volatile("s_waitcnt vmcnt(1)" ::: "memory");
    else        asm volatile("s_waitcnt vmcnt(0)" ::: "memory");
    asm volatile("s_barrier" ::: "memory");        // raw: no lgkm drain
    if (kt < 6) STAGE(kt + 2, (kt + 2) % 3);       // distance-2 prefetch

    // fragments: lane holds k = g*32 + [0,32) of its row as 2 x b128
    // (u_log = 2g, 2g+1), un-swizzled via u_phys = u_log ^ ((row>>2)&3)
    intx8 af, bf;
    {
      const int row = wm * 32 + m32;
      const int x = (row >> 2) & 3;
      int4 lo = *(const int4*)(&As[buf][row * 64 + ((2 * g)     ^ x) * 16]);
      int4 hi = *(const int4*)(&As[buf][row * 64 + ((2 * g + 1) ^ x) * 16]);
      intx8 f; f[0]=lo.x; f[1]=lo.y; f[2]=lo.z; f[3]=lo.w;
               f[4]=hi.x; f[5]=hi.y; f[6]=hi.z; f[7]=hi.w;
      af = f;
    }
    {
      const int row = wn * 32 + m32;
      const int x = (row >> 2) & 3;
      int4 lo = *(const int4*)(&Bs[buf][row * 64 + ((2 * g)     ^ x) * 16]);
      int4 hi = *(const int4*)(&Bs[buf][row * 64 + ((2 * g + 1) ^ x) * 16]);
      intx8 f; f[0]=lo.x; f[1]=lo.y; f[2]=lo.z; f[3]=lo.w;
               f[4]=hi.x; f[5]=hi.y; f[6]=hi.z; f[7]=hi.w;
      bf = f;
    }
    acc = __builtin_amdgcn_mfma_scale_f32_32x32x64_f8f6f4(
        af, bf, acc,
        0 /*A fmt: fp8 e4m3*/, 0 /*B fmt: fp8 e4m3*/,
        0, 127 /*scaleA = 2^0*/, 0, 127 /*scaleB = 2^0*/);
  }

  // Epilogue (R0-verified). 32x32 C/D layout [m74/m101]: col = lane&31,
  // row = (reg&3) + 8*(reg>>2) + 4*(lane>>5), reg in [0,16).
  float lsum = 0.f;
  const bool diag = (bi == bj);
  const int  tc   = tg[colBase + wn * 32 + m32];
  if (!diag) {
#pragma unroll
    for (int q = 0; q < 4; q++) {
      const int4 rlv = *(const int4*)(tg + rowBase + wm * 32 + 4 * g + 8 * q);
      const int rlab[4] = {rlv.x, rlv.y, rlv.z, rlv.w};
#pragma unroll
      for (int j = 0; j < 4; j++) {
        const float s = acc[q * 4 + j];
        lsum += (rlab[j] == tc) ? ((s < 1.f) ? 1.f - s : 0.f)
                                : ((s > MARGIN) ? s : 0.f);
      }
    }
    lsum *= 2.f;     // pair weight hoisted
  } else {
    const int col = colBase + wn * 32 + m32;
#pragma unroll
    for (int q = 0; q < 4; q++) {
      const int rbase = wm * 32 + 4 * g + 8 * q;
      const int4 rlv = *(const int4*)(tg + rowBase + rbase);
      const int rlab[4] = {rlv.x, rlv.y, rlv.z, rlv.w};
#pragma unroll
      for (int j = 0; j < 4; j++) {
        const float s = acc[q * 4 + j];
        float c = (rlab[j] == tc) ? ((s < 1.f) ? 1.f - s : 0.f)
                                  : ((s > MARGIN) ? s : 0.f);
        const int row = rowBase + rbase + j;
        float wgt = (row < col) ? 2.f : ((row == col) ? 1.f : 0.f);
        lsum += wgt * c;
      }
    }
  }

  // block reduce -> ONE atomicAdd per block + completion counter; last
  // block finalizes out (device-scope atomics, m20; fences order acc vs cnt)
#pragma unroll
  for (int off = 32; off > 0; off >>= 1) lsum += __shfl_down(lsum, off, 64);
  if (lane == 0) red[w] = lsum;
  __syncthreads();
  if (tid == 0) {
    float s = 0.f;
#pragma unroll
    for (int i = 0; i < 16; i++) s += red[i];
    atomicAdd(gacc, s);
    __threadfence();
    const unsigned old = atomicAdd(gcnt, 1u);
    if (old == NT - 1) {
      __threadfence();
      const float total = atomicAdd(gacc, 0.f);   // coherent read-back
      out[0] = total * (1.0f / NROWS);
    }
  }
#undef STAGE
}

extern "C" void kernel_launch(void* const* d_in, const int* in_sizes, int n_in,
                              void* d_out, int out_size, void* d_ws, size_t ws_size,
                              hipStream_t stream) {
  const float* x = (const float*)d_in[0];
  const int* tg  = (const int*)d_in[1];
  float* out     = (float*)d_out;
  unsigned char* xb = (unsigned char*)d_ws;                    // fp8 X, 4 MiB
  float* gacc    = (float*)((char*)d_ws + (4u << 20));
  unsigned* gcnt = (unsigned*)((char*)d_ws + (4u << 20) + 16);

  convert_kernel<<<(NROWS * NDIM / 4) / 256, 256, 0, stream>>>(
      (const float4*)x, (unsigned*)xb, gacc, gcnt);
  loss_kernel<<<NT, 1024, 0, stream>>>(xb, tg, gacc, gcnt, out);
}